// Round 17
// baseline (295.953 us; speedup 1.0000x reference)
//
#include <hip/hip_runtime.h>

typedef unsigned short u16;
typedef unsigned int u32;
typedef __attribute__((ext_vector_type(4))) float f32x4;
typedef __attribute__((ext_vector_type(8))) __bf16 bf16x8;
typedef __attribute__((ext_vector_type(8))) u16 u16x8;

// round-to-nearest-even f32 -> bf16 bit pattern
__device__ __forceinline__ u16 f2bf(float x) {
  u32 u = __float_as_uint(x);
  u32 r = (u + 0x7FFFu + ((u >> 16) & 1u)) >> 16;
  return (u16)r;
}

__device__ __forceinline__ float bf2f(u16 b) {
  return __uint_as_float((u32)b << 16);
}

// async global->LDS, 16B per lane. LDS dest = wave-uniform base + lane*16.
__device__ __forceinline__ void gl16(const void* g, void* l) {
  auto* gp = (__attribute__((address_space(1))) u32*)(g);
  auto* lp = (__attribute__((address_space(3))) u32*)(l);
  __builtin_amdgcn_global_load_lds(gp, lp, 16, 0, 0);
}

__device__ __forceinline__ f32x4 mfma16(bf16x8 a, bf16x8 b, f32x4 c) {
  return __builtin_amdgcn_mfma_f32_16x16x32_bf16(a, b, c, 0, 0, 0);
}

__device__ __forceinline__ u16x8 cvt8(const float* p) {
  float4 a = *(const float4*)p, b = *(const float4*)(p + 4);
  u16x8 v;
  v[0] = f2bf(a.x); v[1] = f2bf(a.y); v[2] = f2bf(a.z); v[3] = f2bf(a.w);
  v[4] = f2bf(b.x); v[5] = f2bf(b.y); v[6] = f2bf(b.z); v[7] = f2bf(b.w);
  return v;
}

// ---------------- merged conversion kernel ----------------
// ranges (in 8-elem groups): [0,320000) edge_ctx ; [320000,385536) W_pe ;
// [385536,909824) W_pc ; [909824,942592) W_cc (padded 51->64 rows)
__global__ void k_prep(const float* __restrict__ ec, const float* __restrict__ wpe,
                       const float* __restrict__ wpc, const float* __restrict__ wcc,
                       u16* __restrict__ ecb, u16* __restrict__ wpeb,
                       u16* __restrict__ wpcb, u16* __restrict__ wccb) {
  int i = blockIdx.x * 256 + threadIdx.x;
  if (i < 320000) {
    *(u16x8*)(ecb + (long)i * 8) = cvt8(ec + (long)i * 8);
  } else if (i < 385536) {
    int j = i - 320000;
    *(u16x8*)(wpeb + (long)j * 8) = cvt8(wpe + (long)j * 8);
  } else if (i < 909824) {
    int j = i - 385536;
    *(u16x8*)(wpcb + (long)j * 8) = cvt8(wpc + (long)j * 8);
  } else if (i < 942592) {
    int j = i - 909824;
    long base = (long)j * 8;
    int row = (int)(base >> 12);
    int col = (int)(base & 4095);
    u16x8 v;
    if (row < 51) {
      v = cvt8(wcc + (long)row * 4096 + col);
    } else {
#pragma unroll
      for (int k = 0; k < 8; ++k) v[k] = 0;
    }
    *(u16x8*)(wccb + base) = v;
  }
}

// one 128x128x32 compute step: 8 ds_read_b128 + 16 MFMA (setprio'd)
__device__ __forceinline__ void cstep(const char* sA, const char* sB,
                                      const int (&aOff)[4], const int (&bOff)[4],
                                      f32x4 (&acc)[4][4]) {
  bf16x8 af[4], bv[4];
#pragma unroll
  for (int mi = 0; mi < 4; ++mi) af[mi] = *(const bf16x8*)(sA + aOff[mi]);
#pragma unroll
  for (int ni = 0; ni < 4; ++ni) bv[ni] = *(const bf16x8*)(sB + bOff[ni]);
  __builtin_amdgcn_s_setprio(1);
#pragma unroll
  for (int mi = 0; mi < 4; ++mi)
#pragma unroll
    for (int ni = 0; ni < 4; ++ni)
      acc[mi][ni] = mfma16(af[mi], bv[ni], acc[mi][ni]);
  __builtin_amdgcn_s_setprio(0);
}

// ---------------- GEMM1: edge_rep = relu(edge_ctx @ W_pe.T + b_pe) -> bf16 ----------------
__global__ __launch_bounds__(256, 2) void k_gemm1(const u16* __restrict__ A, const u16* __restrict__ B,
                                                  const float* __restrict__ bias, u16* __restrict__ outp) {
  __shared__ char lds[65536];  // 4 bufs x (A 8K + B 8K)
  int bx = blockIdx.x;
  int rb = bx >> 3, nb = bx & 7;
  int rowBase = rb * 128, nBase = nb * 128;
  int t = threadIdx.x, lane = t & 63, wid = t >> 6;
  int wr = wid >> 1, wc = wid & 1, lm = lane & 15, lg = lane >> 4;
  int ar0 = t >> 2, ar1 = 64 + ar0, c4 = t & 3;
  int sw0 = (c4 * 16) ^ (((ar0 >> 1) & 3) << 4);
  int sw1 = (c4 * 16) ^ (((ar1 >> 1) & 3) << 4);
  const char* aS0 = (const char*)(A + (long)min(rowBase + ar0, 4999) * 512) + sw0;
  const char* aS1 = (const char*)(A + (long)min(rowBase + ar1, 4999) * 512) + sw1;
  const char* bS0 = (const char*)(B + (long)(nBase + ar0) * 512) + sw0;
  const char* bS1 = (const char*)(B + (long)(nBase + ar1) * 512) + sw1;
  int t16 = t * 16;
  int aOff[4], bOff[4];
#pragma unroll
  for (int mi = 0; mi < 4; ++mi) { int r = wr * 64 + mi * 16 + lm; aOff[mi] = r * 64 + ((lg * 16) ^ (((r >> 1) & 3) << 4)); }
#pragma unroll
  for (int ni = 0; ni < 4; ++ni) { int r = wc * 64 + ni * 16 + lm; bOff[ni] = r * 64 + ((lg * 16) ^ (((r >> 1) & 3) << 4)); }
  f32x4 acc[4][4] = {};

#define STAGE_G(k, sb) do { \
    gl16(aS0 + (k) * 2, (sb) + t16); gl16(aS1 + (k) * 2, (sb) + 4096 + t16); \
    gl16(bS0 + (k) * 2, (sb) + 8192 + t16); gl16(bS1 + (k) * 2, (sb) + 12288 + t16); \
  } while (0)

  STAGE_G(0, lds);
  STAGE_G(32, lds + 16384);
  STAGE_G(64, lds + 32768);

  int cur = 0, stg = 3;
  for (int kt = 0; kt < 16; ++kt) {
    if (kt < 13) {
      char* sb = lds + stg * 16384;
      STAGE_G((kt + 3) * 32, sb);
    }
    if (kt < 13)       asm volatile("s_waitcnt vmcnt(12)" ::: "memory");
    else if (kt == 13) asm volatile("s_waitcnt vmcnt(8)" ::: "memory");
    else if (kt == 14) asm volatile("s_waitcnt vmcnt(4)" ::: "memory");
    else               asm volatile("s_waitcnt vmcnt(0)" ::: "memory");
    __builtin_amdgcn_s_barrier();
    char* cb = lds + cur * 16384;
    cstep(cb, cb + 8192, aOff, bOff, acc);
    __builtin_amdgcn_s_barrier();
    cur = (cur == 3) ? 0 : cur + 1;
    stg = (stg == 3) ? 0 : stg + 1;
  }
#undef STAGE_G

#pragma unroll
  for (int mi = 0; mi < 4; ++mi)
#pragma unroll
    for (int ni = 0; ni < 4; ++ni) {
      int n = nBase + wc * 64 + ni * 16 + lm;
      float bvv = bias[n];
#pragma unroll
      for (int rg = 0; rg < 4; ++rg) {
        int r = rowBase + wr * 64 + mi * 16 + lg * 4 + rg;
        if (r < 5000) {
          float v = acc[mi][ni][rg] + bvv;
          v = v > 0.f ? v : 0.f;
          outp[(long)r * 1024 + n] = f2bf(v);
        }
      }
    }
}

// ---------------- GEMM2': H = head_rep @ W_pc[:,:512].T + b_pc ; T = tail_rep @ W_pc[:,512:].T ----------------
// gemm1-identical 4-deep BK=32 pipeline (counted vmcnt(12)), K=512. grid = 2560 (h x 40 rb x 32 nb).
__global__ __launch_bounds__(256, 2) void k_gemm2(const u16* __restrict__ erep, const u16* __restrict__ wpc,
                                                  const float* __restrict__ bpc, u16* __restrict__ Hout,
                                                  u16* __restrict__ Tout) {
  __shared__ char lds[65536];  // 4 bufs x (A 8K + B 8K)
  int bx = blockIdx.x;
  int h = (bx >= 1280) ? 1 : 0;
  int rr = bx - h * 1280;
  int rb = rr >> 5, nb = rr & 31;
  int rowBase = rb * 128, nBase = nb * 128;
  u16* outp = h ? Tout : Hout;
  int t = threadIdx.x, lane = t & 63, wid = t >> 6;
  int wr = wid >> 1, wc = wid & 1, lm = lane & 15, lg = lane >> 4;
  int ar0 = t >> 2, ar1 = 64 + ar0, c4 = t & 3;
  int sw0 = (c4 * 16) ^ (((ar0 >> 1) & 3) << 4);
  int sw1 = (c4 * 16) ^ (((ar1 >> 1) & 3) << 4);
  const char* aS0 = (const char*)(erep + (long)min(rowBase + ar0, 4999) * 1024 + h * 512) + sw0;
  const char* aS1 = (const char*)(erep + (long)min(rowBase + ar1, 4999) * 1024 + h * 512) + sw1;
  const char* bS0 = (const char*)(wpc + (long)(nBase + ar0) * 1024 + h * 512) + sw0;
  const char* bS1 = (const char*)(wpc + (long)(nBase + ar1) * 1024 + h * 512) + sw1;
  int t16 = t * 16;
  int aOff[4], bOff[4];
#pragma unroll
  for (int mi = 0; mi < 4; ++mi) { int r = wr * 64 + mi * 16 + lm; aOff[mi] = r * 64 + ((lg * 16) ^ (((r >> 1) & 3) << 4)); }
#pragma unroll
  for (int ni = 0; ni < 4; ++ni) { int r = wc * 64 + ni * 16 + lm; bOff[ni] = r * 64 + ((lg * 16) ^ (((r >> 1) & 3) << 4)); }
  f32x4 acc[4][4] = {};

#define STAGE_G2(k, sb) do { \
    gl16(aS0 + (k) * 2, (sb) + t16); gl16(aS1 + (k) * 2, (sb) + 4096 + t16); \
    gl16(bS0 + (k) * 2, (sb) + 8192 + t16); gl16(bS1 + (k) * 2, (sb) + 12288 + t16); \
  } while (0)

  STAGE_G2(0, lds);
  STAGE_G2(32, lds + 16384);
  STAGE_G2(64, lds + 32768);

  int cur = 0, stg = 3;
  for (int kt = 0; kt < 16; ++kt) {
    if (kt < 13) {
      char* sb = lds + stg * 16384;
      STAGE_G2((kt + 3) * 32, sb);
    }
    if (kt < 13)       asm volatile("s_waitcnt vmcnt(12)" ::: "memory");
    else if (kt == 13) asm volatile("s_waitcnt vmcnt(8)" ::: "memory");
    else if (kt == 14) asm volatile("s_waitcnt vmcnt(4)" ::: "memory");
    else               asm volatile("s_waitcnt vmcnt(0)" ::: "memory");
    __builtin_amdgcn_s_barrier();
    char* cb = lds + cur * 16384;
    cstep(cb, cb + 8192, aOff, bOff, acc);
    __builtin_amdgcn_s_barrier();
    cur = (cur == 3) ? 0 : cur + 1;
    stg = (stg == 3) ? 0 : stg + 1;
  }
#undef STAGE_G2

#pragma unroll
  for (int mi = 0; mi < 4; ++mi)
#pragma unroll
    for (int ni = 0; ni < 4; ++ni) {
      int n = nBase + wc * 64 + ni * 16 + lm;
      float bvv = h ? 0.f : bpc[n];
#pragma unroll
      for (int rg = 0; rg < 4; ++rg) {
        int r = rowBase + wr * 64 + mi * 16 + lg * 4 + rg;
        if (r < 5000) {
          float v = acc[mi][ni][rg] + bvv;
          outp[(long)r * 4096 + n] = f2bf(v);
        }
      }
    }
}

// ---------------- k_mul: P[r,:] = bf16((H[hi[r],:] + T[ti[r],:]) * union[r,:]) ----------------
// Pure streaming/gather kernel: no LDS, no barriers, ~full occupancy. 8 elems/thread/iter.
__global__ void k_mul(const u16* __restrict__ H, const u16* __restrict__ T,
                      const float* __restrict__ un, const int* __restrict__ pidx,
                      u16* __restrict__ P) {
  long stride = (long)gridDim.x * 256;
  for (long g = (long)blockIdx.x * 256 + threadIdx.x; g < 10240000; g += stride) {
    int row = (int)(g >> 9);
    int c8 = ((int)g & 511) * 8;
    int hi = pidx[2 * row], ti = pidx[2 * row + 1];
    u16x8 h8 = *(const u16x8*)(H + (long)hi * 4096 + c8);
    u16x8 t8 = *(const u16x8*)(T + (long)ti * 4096 + c8);
    const float* up = un + (long)row * 4096 + c8;
    float4 u0 = *(const float4*)up, u1 = *(const float4*)(up + 4);
    float uu[8];
    *(float4*)(uu) = u0;
    *(float4*)(uu + 4) = u1;
    bf16x8 pv;
#pragma unroll
    for (int j = 0; j < 8; ++j)
      pv[j] = (__bf16)((bf2f(h8[j]) + bf2f(t8[j])) * uu[j]);
    *(bf16x8*)(P + g * 8) = pv;
  }
}

// ---------------- k_gemm3: partial[ks] = P[:, ks*512:+512] @ W_cc[:, ks*512:+512]^T ----------------
// gemm1-style 4-deep pipeline; 128 rows x 64 cols per block; K-split 8 x 512.
// grid = 157 x 8 = 1256. LDS: 4 bufs x (A 8K + W 4K) = 48 KB.
__global__ __launch_bounds__(256, 2) void k_gemm3(const u16* __restrict__ P, const u16* __restrict__ wcc,
                                                  float* __restrict__ partial) {
  __shared__ char lds[49152];
  int bx = blockIdx.x;
  int rb = bx >> 3, ks = bx & 7;
  int rowBase = rb * 128;
  long ksB = (long)ks * 1024;  // byte offset of K-segment within a 8192B row
  int t = threadIdx.x, lane = t & 63, wid = t >> 6;
  int lm = lane & 15, lg = lane >> 4;
  int ar0 = t >> 2, ar1 = 64 + ar0, c4 = t & 3;
  int sw0 = (c4 * 16) ^ (((ar0 >> 1) & 3) << 4);
  int sw1 = (c4 * 16) ^ (((ar1 >> 1) & 3) << 4);
  const char* aS0 = (const char*)P + (long)min(rowBase + ar0, 19999) * 8192 + ksB + sw0;
  const char* aS1 = (const char*)P + (long)min(rowBase + ar1, 19999) * 8192 + ksB + sw1;
  const char* wS  = (const char*)wcc + (long)ar0 * 8192 + ksB + sw0;  // W row = t>>2 (0..63)
  int t16 = t * 16;
  int aOff[2], bOff[4];
#pragma unroll
  for (int m2 = 0; m2 < 2; ++m2) { int r = wid * 32 + m2 * 16 + lm; aOff[m2] = r * 64 + ((lg * 16) ^ (((r >> 1) & 3) << 4)); }
#pragma unroll
  for (int ni = 0; ni < 4; ++ni) { int c = ni * 16 + lm; bOff[ni] = 8192 + c * 64 + ((lg * 16) ^ (((c >> 1) & 3) << 4)); }
  f32x4 acc[2][4] = {};

#define STAGE_G3(k, sb) do { \
    gl16(aS0 + (k) * 2, (sb) + t16); gl16(aS1 + (k) * 2, (sb) + 4096 + t16); \
    gl16(wS + (k) * 2, (sb) + 8192 + t16); \
  } while (0)

  STAGE_G3(0, lds);
  STAGE_G3(32, lds + 12288);
  STAGE_G3(64, lds + 24576);

  int cur = 0, stg = 3;
  for (int kt = 0; kt < 16; ++kt) {
    if (kt < 13) {
      char* sb = lds + stg * 12288;
      STAGE_G3((kt + 3) * 32, sb);
    }
    if (kt < 13)       asm volatile("s_waitcnt vmcnt(9)" ::: "memory");
    else if (kt == 13) asm volatile("s_waitcnt vmcnt(6)" ::: "memory");
    else if (kt == 14) asm volatile("s_waitcnt vmcnt(3)" ::: "memory");
    else               asm volatile("s_waitcnt vmcnt(0)" ::: "memory");
    __builtin_amdgcn_s_barrier();
    char* cb = lds + cur * 12288;
    {
      bf16x8 aU[2], bW[4];
#pragma unroll
      for (int m2 = 0; m2 < 2; ++m2) aU[m2] = *(const bf16x8*)(cb + aOff[m2]);
#pragma unroll
      for (int ni = 0; ni < 4; ++ni) bW[ni] = *(const bf16x8*)(cb + bOff[ni]);
      __builtin_amdgcn_s_setprio(1);
#pragma unroll
      for (int m2 = 0; m2 < 2; ++m2)
#pragma unroll
        for (int ni = 0; ni < 4; ++ni)
          acc[m2][ni] = mfma16(aU[m2], bW[ni], acc[m2][ni]);
      __builtin_amdgcn_s_setprio(0);
    }
    __builtin_amdgcn_s_barrier();
    cur = (cur == 3) ? 0 : cur + 1;
    stg = (stg == 3) ? 0 : stg + 1;
  }
#undef STAGE_G3

#pragma unroll
  for (int m2 = 0; m2 < 2; ++m2)
#pragma unroll
    for (int rg = 0; rg < 4; ++rg) {
      int r = wid * 32 + m2 * 16 + lg * 4 + rg;
      int rG = rowBase + r;
      if (rG < 20000) {
        long base = ((long)ks * 20000 + rG) * 64;
#pragma unroll
        for (int ni = 0; ni < 4; ++ni) {
          int c = ni * 16 + lm;
          if (c < 51) partial[base + c] = acc[m2][ni][rg];
        }
      }
    }
}

// ---------------- reduce: out = sum_ks partial + b_cc + freq ----------------
__global__ void k_red(const float* __restrict__ partial, const float* __restrict__ bcc,
                      const float* __restrict__ freq, const int* __restrict__ preds,
                      const int* __restrict__ pidx, float* __restrict__ outp) {
  int idx = blockIdx.x * 256 + threadIdx.x;   // over 20000*64
  if (idx >= 20000 * 64) return;
  int row = idx >> 6, c = idx & 63;
  if (c >= 51) return;
  float s = 0.f;
#pragma unroll
  for (int i = 0; i < 8; ++i) s += partial[((long)i * 20000 + row) * 64 + c];
  int lbl = preds[pidx[2 * row]] * 151 + preds[pidx[2 * row + 1]];
  outp[(long)row * 51 + c] = s + bcc[c] + freq[(long)lbl * 51 + c];
}

extern "C" void kernel_launch(void* const* d_in, const int* in_sizes, int n_in,
                              void* d_out, int out_size, void* d_ws, size_t ws_size,
                              hipStream_t stream) {
  const float* edge_ctx = (const float*)d_in[0];
  const float* unionf   = (const float*)d_in[1];
  const float* W_pe     = (const float*)d_in[2];
  const float* b_pe     = (const float*)d_in[3];
  const float* W_pc     = (const float*)d_in[4];
  const float* b_pc     = (const float*)d_in[5];
  const float* W_cc     = (const float*)d_in[6];
  const float* b_cc     = (const float*)d_in[7];
  const float* freq     = (const float*)d_in[8];
  const int*   preds    = (const int*)d_in[9];
  const int*   pidx     = (const int*)d_in[10];
  float* out = (float*)d_out;
  char* ws = (char*)d_ws;

  u16* Hb    = (u16*)(ws + 0);           // 5000*4096 bf16 = 40,960,000 B
  u16* Tb    = (u16*)(ws + 40960000);    // 5000*4096 bf16
  u16* erep  = (u16*)(ws + 81920000);    // 5000*1024 bf16
  u16* wpcb  = (u16*)(ws + 92160000);    // 4096*1024 bf16
  u16* wccb  = (u16*)(ws + 100548608);   // 64*4096  bf16
  u16* ecb   = (u16*)(ws + 101072896);   // 5000*512 bf16
  u16* wpeb  = (u16*)(ws + 106192896);   // 1024*512 bf16
  float* par = (float*)(ws + 107241472); // 8*20000*64 f32 = 40,960,000 B
  u16* Pb    = (u16*)(ws + 148201472);   // 20000*4096 bf16 = 163,840,000 B (total ~312 MB)

  k_prep<<<3682, 256, 0, stream>>>(edge_ctx, W_pe, W_pc, W_cc, ecb, wpeb, wpcb, wccb);
  k_gemm1<<<320, 256, 0, stream>>>(ecb, wpeb, b_pe, erep);
  k_gemm2<<<2560, 256, 0, stream>>>(erep, wpcb, b_pc, Hb, Tb);
  k_mul<<<2048, 256, 0, stream>>>(Hb, Tb, unionf, pidx, Pb);
  k_gemm3<<<1256, 256, 0, stream>>>(Pb, wccb, par);
  k_red<<<5000, 256, 0, stream>>>(par, b_cc, freq, preds, pidx, out);
}

// Round 18
// 271.578 us; speedup vs baseline: 1.0898x; 1.0898x over previous
//
#include <hip/hip_runtime.h>

typedef unsigned short u16;
typedef unsigned int u32;
typedef __attribute__((ext_vector_type(4))) float f32x4;
typedef __attribute__((ext_vector_type(8))) __bf16 bf16x8;
typedef __attribute__((ext_vector_type(8))) u16 u16x8;

// round-to-nearest-even f32 -> bf16 bit pattern
__device__ __forceinline__ u16 f2bf(float x) {
  u32 u = __float_as_uint(x);
  u32 r = (u + 0x7FFFu + ((u >> 16) & 1u)) >> 16;
  return (u16)r;
}

__device__ __forceinline__ float bf2f(u16 b) {
  return __uint_as_float((u32)b << 16);
}

// async global->LDS, 16B per lane. LDS dest = wave-uniform base + lane*16.
__device__ __forceinline__ void gl16(const void* g, void* l) {
  auto* gp = (__attribute__((address_space(1))) u32*)(g);
  auto* lp = (__attribute__((address_space(3))) u32*)(l);
  __builtin_amdgcn_global_load_lds(gp, lp, 16, 0, 0);
}

__device__ __forceinline__ f32x4 mfma16(bf16x8 a, bf16x8 b, f32x4 c) {
  return __builtin_amdgcn_mfma_f32_16x16x32_bf16(a, b, c, 0, 0, 0);
}

__device__ __forceinline__ u16x8 cvt8(const float* p) {
  float4 a = *(const float4*)p, b = *(const float4*)(p + 4);
  u16x8 v;
  v[0] = f2bf(a.x); v[1] = f2bf(a.y); v[2] = f2bf(a.z); v[3] = f2bf(a.w);
  v[4] = f2bf(b.x); v[5] = f2bf(b.y); v[6] = f2bf(b.z); v[7] = f2bf(b.w);
  return v;
}

// ---------------- merged conversion kernel ----------------
// ranges (in 8-elem groups): [0,320000) edge_ctx ; [320000,385536) W_pe ;
// [385536,909824) W_pc ; [909824,942592) W_cc (padded 51->64 rows)
__global__ void k_prep(const float* __restrict__ ec, const float* __restrict__ wpe,
                       const float* __restrict__ wpc, const float* __restrict__ wcc,
                       u16* __restrict__ ecb, u16* __restrict__ wpeb,
                       u16* __restrict__ wpcb, u16* __restrict__ wccb) {
  int i = blockIdx.x * 256 + threadIdx.x;
  if (i < 320000) {
    *(u16x8*)(ecb + (long)i * 8) = cvt8(ec + (long)i * 8);
  } else if (i < 385536) {
    int j = i - 320000;
    *(u16x8*)(wpeb + (long)j * 8) = cvt8(wpe + (long)j * 8);
  } else if (i < 909824) {
    int j = i - 385536;
    *(u16x8*)(wpcb + (long)j * 8) = cvt8(wpc + (long)j * 8);
  } else if (i < 942592) {
    int j = i - 909824;
    long base = (long)j * 8;
    int row = (int)(base >> 12);
    int col = (int)(base & 4095);
    u16x8 v;
    if (row < 51) {
      v = cvt8(wcc + (long)row * 4096 + col);
    } else {
#pragma unroll
      for (int k = 0; k < 8; ++k) v[k] = 0;
    }
    *(u16x8*)(wccb + base) = v;
  }
}

// one 128x128x32 compute step: 8 ds_read_b128 + 16 MFMA (setprio'd)
__device__ __forceinline__ void cstep(const char* sA, const char* sB,
                                      const int (&aOff)[4], const int (&bOff)[4],
                                      f32x4 (&acc)[4][4]) {
  bf16x8 af[4], bv[4];
#pragma unroll
  for (int mi = 0; mi < 4; ++mi) af[mi] = *(const bf16x8*)(sA + aOff[mi]);
#pragma unroll
  for (int ni = 0; ni < 4; ++ni) bv[ni] = *(const bf16x8*)(sB + bOff[ni]);
  __builtin_amdgcn_s_setprio(1);
#pragma unroll
  for (int mi = 0; mi < 4; ++mi)
#pragma unroll
    for (int ni = 0; ni < 4; ++ni)
      acc[mi][ni] = mfma16(af[mi], bv[ni], acc[mi][ni]);
  __builtin_amdgcn_s_setprio(0);
}

// ---------------- GEMM1: edge_rep = relu(edge_ctx @ W_pe.T + b_pe) -> bf16 ----------------
__global__ __launch_bounds__(256, 2) void k_gemm1(const u16* __restrict__ A, const u16* __restrict__ B,
                                                  const float* __restrict__ bias, u16* __restrict__ outp) {
  __shared__ char lds[65536];  // 4 bufs x (A 8K + B 8K)
  int bx = blockIdx.x;
  int rb = bx >> 3, nb = bx & 7;
  int rowBase = rb * 128, nBase = nb * 128;
  int t = threadIdx.x, lane = t & 63, wid = t >> 6;
  int wr = wid >> 1, wc = wid & 1, lm = lane & 15, lg = lane >> 4;
  int ar0 = t >> 2, ar1 = 64 + ar0, c4 = t & 3;
  int sw0 = (c4 * 16) ^ (((ar0 >> 1) & 3) << 4);
  int sw1 = (c4 * 16) ^ (((ar1 >> 1) & 3) << 4);
  const char* aS0 = (const char*)(A + (long)min(rowBase + ar0, 4999) * 512) + sw0;
  const char* aS1 = (const char*)(A + (long)min(rowBase + ar1, 4999) * 512) + sw1;
  const char* bS0 = (const char*)(B + (long)(nBase + ar0) * 512) + sw0;
  const char* bS1 = (const char*)(B + (long)(nBase + ar1) * 512) + sw1;
  int t16 = t * 16;
  int aOff[4], bOff[4];
#pragma unroll
  for (int mi = 0; mi < 4; ++mi) { int r = wr * 64 + mi * 16 + lm; aOff[mi] = r * 64 + ((lg * 16) ^ (((r >> 1) & 3) << 4)); }
#pragma unroll
  for (int ni = 0; ni < 4; ++ni) { int r = wc * 64 + ni * 16 + lm; bOff[ni] = r * 64 + ((lg * 16) ^ (((r >> 1) & 3) << 4)); }
  f32x4 acc[4][4] = {};

#define STAGE_G(k, sb) do { \
    gl16(aS0 + (k) * 2, (sb) + t16); gl16(aS1 + (k) * 2, (sb) + 4096 + t16); \
    gl16(bS0 + (k) * 2, (sb) + 8192 + t16); gl16(bS1 + (k) * 2, (sb) + 12288 + t16); \
  } while (0)

  STAGE_G(0, lds);
  STAGE_G(32, lds + 16384);
  STAGE_G(64, lds + 32768);

  int cur = 0, stg = 3;
  for (int kt = 0; kt < 16; ++kt) {
    if (kt < 13) {
      char* sb = lds + stg * 16384;
      STAGE_G((kt + 3) * 32, sb);
    }
    if (kt < 13)       asm volatile("s_waitcnt vmcnt(12)" ::: "memory");
    else if (kt == 13) asm volatile("s_waitcnt vmcnt(8)" ::: "memory");
    else if (kt == 14) asm volatile("s_waitcnt vmcnt(4)" ::: "memory");
    else               asm volatile("s_waitcnt vmcnt(0)" ::: "memory");
    __builtin_amdgcn_s_barrier();
    char* cb = lds + cur * 16384;
    cstep(cb, cb + 8192, aOff, bOff, acc);
    __builtin_amdgcn_s_barrier();
    cur = (cur == 3) ? 0 : cur + 1;
    stg = (stg == 3) ? 0 : stg + 1;
  }
#undef STAGE_G

#pragma unroll
  for (int mi = 0; mi < 4; ++mi)
#pragma unroll
    for (int ni = 0; ni < 4; ++ni) {
      int n = nBase + wc * 64 + ni * 16 + lm;
      float bvv = bias[n];
#pragma unroll
      for (int rg = 0; rg < 4; ++rg) {
        int r = rowBase + wr * 64 + mi * 16 + lg * 4 + rg;
        if (r < 5000) {
          float v = acc[mi][ni][rg] + bvv;
          v = v > 0.f ? v : 0.f;
          outp[(long)r * 1024 + n] = f2bf(v);
        }
      }
    }
}

// ---------------- GEMM2': H = head_rep @ W_pc[:,:512].T + b_pc ; T = tail_rep @ W_pc[:,512:].T ----------------
// gemm1-identical 4-deep BK=32 pipeline (counted vmcnt(12)), K=512. grid = 2560 (h x 40 rb x 32 nb).
// T1 XCD-aware swizzle: consecutive logical blocks (same A-panel) land on one XCD's L2.
__global__ __launch_bounds__(256, 2) void k_gemm2(const u16* __restrict__ erep, const u16* __restrict__ wpc,
                                                  const float* __restrict__ bpc, u16* __restrict__ Hout,
                                                  u16* __restrict__ Tout) {
  __shared__ char lds[65536];  // 4 bufs x (A 8K + B 8K)
  int bx0 = blockIdx.x;
  int bx = (bx0 & 7) * 320 + (bx0 >> 3);  // 2560 % 8 == 0 -> bijective XCD swizzle
  int h = (bx >= 1280) ? 1 : 0;
  int rr = bx - h * 1280;
  int rb = rr >> 5, nb = rr & 31;
  int rowBase = rb * 128, nBase = nb * 128;
  u16* outp = h ? Tout : Hout;
  int t = threadIdx.x, lane = t & 63, wid = t >> 6;
  int wr = wid >> 1, wc = wid & 1, lm = lane & 15, lg = lane >> 4;
  int ar0 = t >> 2, ar1 = 64 + ar0, c4 = t & 3;
  int sw0 = (c4 * 16) ^ (((ar0 >> 1) & 3) << 4);
  int sw1 = (c4 * 16) ^ (((ar1 >> 1) & 3) << 4);
  const char* aS0 = (const char*)(erep + (long)min(rowBase + ar0, 4999) * 1024 + h * 512) + sw0;
  const char* aS1 = (const char*)(erep + (long)min(rowBase + ar1, 4999) * 1024 + h * 512) + sw1;
  const char* bS0 = (const char*)(wpc + (long)(nBase + ar0) * 1024 + h * 512) + sw0;
  const char* bS1 = (const char*)(wpc + (long)(nBase + ar1) * 1024 + h * 512) + sw1;
  int t16 = t * 16;
  int aOff[4], bOff[4];
#pragma unroll
  for (int mi = 0; mi < 4; ++mi) { int r = wr * 64 + mi * 16 + lm; aOff[mi] = r * 64 + ((lg * 16) ^ (((r >> 1) & 3) << 4)); }
#pragma unroll
  for (int ni = 0; ni < 4; ++ni) { int r = wc * 64 + ni * 16 + lm; bOff[ni] = r * 64 + ((lg * 16) ^ (((r >> 1) & 3) << 4)); }
  f32x4 acc[4][4] = {};

#define STAGE_G2(k, sb) do { \
    gl16(aS0 + (k) * 2, (sb) + t16); gl16(aS1 + (k) * 2, (sb) + 4096 + t16); \
    gl16(bS0 + (k) * 2, (sb) + 8192 + t16); gl16(bS1 + (k) * 2, (sb) + 12288 + t16); \
  } while (0)

  STAGE_G2(0, lds);
  STAGE_G2(32, lds + 16384);
  STAGE_G2(64, lds + 32768);

  int cur = 0, stg = 3;
  for (int kt = 0; kt < 16; ++kt) {
    if (kt < 13) {
      char* sb = lds + stg * 16384;
      STAGE_G2((kt + 3) * 32, sb);
    }
    if (kt < 13)       asm volatile("s_waitcnt vmcnt(12)" ::: "memory");
    else if (kt == 13) asm volatile("s_waitcnt vmcnt(8)" ::: "memory");
    else if (kt == 14) asm volatile("s_waitcnt vmcnt(4)" ::: "memory");
    else               asm volatile("s_waitcnt vmcnt(0)" ::: "memory");
    __builtin_amdgcn_s_barrier();
    char* cb = lds + cur * 16384;
    cstep(cb, cb + 8192, aOff, bOff, acc);
    __builtin_amdgcn_s_barrier();
    cur = (cur == 3) ? 0 : cur + 1;
    stg = (stg == 3) ? 0 : stg + 1;
  }
#undef STAGE_G2

#pragma unroll
  for (int mi = 0; mi < 4; ++mi)
#pragma unroll
    for (int ni = 0; ni < 4; ++ni) {
      int n = nBase + wc * 64 + ni * 16 + lm;
      float bvv = h ? 0.f : bpc[n];
#pragma unroll
      for (int rg = 0; rg < 4; ++rg) {
        int r = rowBase + wr * 64 + mi * 16 + lg * 4 + rg;
        if (r < 5000) {
          float v = acc[mi][ni][rg] + bvv;
          outp[(long)r * 4096 + n] = f2bf(v);
        }
      }
    }
}

// ---------------- final: P = (H[hi] + T[ti]) * union ; partial[ps] = P_slice @ W_cc.T ----------------
// grid = 313 row-blocks (64 rows) x 8 pc-slices (512 cols, 4 chunks of 128). 256 threads, 4 waves.
// Chunk-pipelined, bW preloaded before prefetch (counted wait), double-buffered sU. (R14 best-measured)
__global__ __launch_bounds__(256) void k_final(
    const u16* __restrict__ H, const u16* __restrict__ T,
    const u16* __restrict__ wcc,   // [64][4096] bf16 padded
    const float* __restrict__ un,  // [20000][4096] f32
    const int* __restrict__ pidx,
    float* __restrict__ partial) { // [8][20000][64] f32
  __shared__ char sU[2][16384];   // [64][128] bf16 swizzled, double-buffered
  int bx = blockIdx.x;
  int rb = bx >> 3, ps = bx & 7;
  int rowBase = rb * 64;
  int t = threadIdx.x, lane = t & 63, wid = t >> 6;
  int lm = lane & 15, lg = lane >> 4;
  int r16 = t >> 4, c16 = t & 15;

  // u32 byte offsets for the 4 gathered rows this thread touches (16 lanes/row -> 256B coalesced)
  u32 hoff[4], toff[4], uoff[4];
#pragma unroll
  for (int p = 0; p < 4; ++p) {
    int rG = min(rowBase + p * 16 + r16, 19999);
    hoff[p] = (u32)pidx[2 * rG] * 8192u + (u32)c16 * 16u;
    toff[p] = (u32)pidx[2 * rG + 1] * 8192u + (u32)c16 * 16u;
    uoff[p] = (u32)rG * 16384u + (u32)c16 * 32u;
  }
  const char* Hc = (const char*)H;
  const char* Tc = (const char*)T;
  const char* Uc = (const char*)un;
  int pc0 = ps * 512;

  u16x8 h8[4], t8[4];
  float4 u0[4], u1[4];

#define ISSUE(pcB) do { \
    _Pragma("unroll") \
    for (int p = 0; p < 4; ++p) { \
      h8[p] = *(const u16x8*)(Hc + hoff[p] + (u32)(pcB) * 2u); \
      t8[p] = *(const u16x8*)(Tc + toff[p] + (u32)(pcB) * 2u); \
      u0[p] = *(const float4*)(Uc + uoff[p] + (u32)(pcB) * 4u); \
      u1[p] = *(const float4*)(Uc + uoff[p] + (u32)(pcB) * 4u + 16u); \
    } \
  } while (0)

  f32x4 outAcc[4] = {};

  ISSUE(pc0);  // chunk 0 loads

  for (int chk = 0; chk < 4; ++chk) {
    int pcBase = pc0 + chk * 128;
    asm volatile("s_waitcnt vmcnt(0)" ::: "memory");  // chunk's H/T/U arrived
    char* sUb = sU[chk & 1];
#pragma unroll
    for (int p = 0; p < 4; ++p) {
      int r = p * 16 + r16;
      float uu[8];
      *(float4*)(uu) = u0[p];
      *(float4*)(uu + 4) = u1[p];
      bf16x8 pv;
#pragma unroll
      for (int j = 0; j < 8; ++j)
        pv[j] = (__bf16)((bf2f(h8[p][j]) + bf2f(t8[p][j])) * uu[j]);
      *(bf16x8*)(sUb + r * 256 + ((c16 * 16) ^ ((r & 7) << 4))) = pv;
    }
    // bW preload for THIS chunk — issued BEFORE the prefetch so its wait is counted,
    // leaving the prefetch in flight across barrier + MFMAs.
    bf16x8 bW[4][4];
#pragma unroll
    for (int kb = 0; kb < 4; ++kb)
#pragma unroll
      for (int ni = 0; ni < 4; ++ni)
        bW[kb][ni] = *(const bf16x8*)(wcc + (long)(ni * 16 + lm) * 4096 + pcBase + kb * 32 + lg * 8);
    if (chk < 3) ISSUE(pcBase + 128);  // prefetch next chunk; rides under barrier+GEMM3
    asm volatile("s_waitcnt lgkmcnt(0)" ::: "memory");
    __builtin_amdgcn_s_barrier();      // sU[chk&1] writes visible; prev buffer freed

    // GEMM3 partial: outAcc += sU(64x128) @ W_cc_chunk(64x128)^T (wave owns rows wid*16..+16)
#pragma unroll
    for (int kb = 0; kb < 4; ++kb) {
      int r = wid * 16 + lm;
      bf16x8 aU = *(const bf16x8*)(sUb + r * 256 + ((kb * 64 + lg * 16) ^ ((r & 7) << 4)));
      __builtin_amdgcn_s_setprio(1);
#pragma unroll
      for (int ni = 0; ni < 4; ++ni)
        outAcc[ni] = mfma16(aU, bW[kb][ni], outAcc[ni]);
      __builtin_amdgcn_s_setprio(0);
    }
  }
#undef ISSUE

  // write-once partial slice (no atomics)
#pragma unroll
  for (int rg = 0; rg < 4; ++rg) {
    int r = wid * 16 + lg * 4 + rg;
    int rG = rowBase + r;
    if (rG < 20000) {
      long base = ((long)ps * 20000 + rG) * 64;
#pragma unroll
      for (int ni = 0; ni < 4; ++ni) {
        int c = ni * 16 + lm;
        if (c < 51) partial[base + c] = outAcc[ni][rg];
      }
    }
  }
}

// ---------------- reduce: out = sum_ps partial + b_cc + freq ----------------
__global__ void k_red(const float* __restrict__ partial, const float* __restrict__ bcc,
                      const float* __restrict__ freq, const int* __restrict__ preds,
                      const int* __restrict__ pidx, float* __restrict__ outp) {
  int idx = blockIdx.x * 256 + threadIdx.x;   // over 20000*64
  if (idx >= 20000 * 64) return;
  int row = idx >> 6, c = idx & 63;
  if (c >= 51) return;
  float s = 0.f;
#pragma unroll
  for (int i = 0; i < 8; ++i) s += partial[((long)i * 20000 + row) * 64 + c];
  int lbl = preds[pidx[2 * row]] * 151 + preds[pidx[2 * row + 1]];
  outp[(long)row * 51 + c] = s + bcc[c] + freq[(long)lbl * 51 + c];
}

extern "C" void kernel_launch(void* const* d_in, const int* in_sizes, int n_in,
                              void* d_out, int out_size, void* d_ws, size_t ws_size,
                              hipStream_t stream) {
  const float* edge_ctx = (const float*)d_in[0];
  const float* unionf   = (const float*)d_in[1];
  const float* W_pe     = (const float*)d_in[2];
  const float* b_pe     = (const float*)d_in[3];
  const float* W_pc     = (const float*)d_in[4];
  const float* b_pc     = (const float*)d_in[5];
  const float* W_cc     = (const float*)d_in[6];
  const float* b_cc     = (const float*)d_in[7];
  const float* freq     = (const float*)d_in[8];
  const int*   preds    = (const int*)d_in[9];
  const int*   pidx     = (const int*)d_in[10];
  float* out = (float*)d_out;
  char* ws = (char*)d_ws;

  u16* Hb    = (u16*)(ws + 0);           // 5000*4096 bf16 = 40,960,000 B
  u16* Tb    = (u16*)(ws + 40960000);    // 5000*4096 bf16
  u16* erep  = (u16*)(ws + 81920000);    // 5000*1024 bf16
  u16* wpcb  = (u16*)(ws + 92160000);    // 4096*1024 bf16
  u16* wccb  = (u16*)(ws + 100548608);   // 64*4096  bf16
  u16* ecb   = (u16*)(ws + 101072896);   // 5000*512 bf16
  u16* wpeb  = (u16*)(ws + 106192896);   // 1024*512 bf16
  float* par = (float*)(ws + 107241472); // 8*20000*64 f32 = 40,960,000 B (total ~148.2 MB)

  k_prep<<<3682, 256, 0, stream>>>(edge_ctx, W_pe, W_pc, W_cc, ecb, wpeb, wpcb, wccb);
  k_gemm1<<<320, 256, 0, stream>>>(ecb, wpeb, b_pe, erep);
  k_gemm2<<<2560, 256, 0, stream>>>(erep, wpcb, b_pc, Hb, Tb);
  k_final<<<2504, 256, 0, stream>>>(Hb, Tb, wccb, unionf, pidx, par);
  k_red<<<5000, 256, 0, stream>>>(par, b_cc, freq, preds, pidx, out);
}

// Round 19
// 259.026 us; speedup vs baseline: 1.1426x; 1.0485x over previous
//
#include <hip/hip_runtime.h>

typedef unsigned short u16;
typedef unsigned int u32;
typedef __attribute__((ext_vector_type(4))) float f32x4;
typedef __attribute__((ext_vector_type(8))) __bf16 bf16x8;
typedef __attribute__((ext_vector_type(8))) u16 u16x8;

// round-to-nearest-even f32 -> bf16 bit pattern
__device__ __forceinline__ u16 f2bf(float x) {
  u32 u = __float_as_uint(x);
  u32 r = (u + 0x7FFFu + ((u >> 16) & 1u)) >> 16;
  return (u16)r;
}

__device__ __forceinline__ float bf2f(u16 b) {
  return __uint_as_float((u32)b << 16);
}

// async global->LDS, 16B per lane. LDS dest = wave-uniform base + lane*16.
__device__ __forceinline__ void gl16(const void* g, void* l) {
  auto* gp = (__attribute__((address_space(1))) u32*)(g);
  auto* lp = (__attribute__((address_space(3))) u32*)(l);
  __builtin_amdgcn_global_load_lds(gp, lp, 16, 0, 0);
}

__device__ __forceinline__ f32x4 mfma16(bf16x8 a, bf16x8 b, f32x4 c) {
  return __builtin_amdgcn_mfma_f32_16x16x32_bf16(a, b, c, 0, 0, 0);
}

__device__ __forceinline__ u16x8 cvt8(const float* p) {
  float4 a = *(const float4*)p, b = *(const float4*)(p + 4);
  u16x8 v;
  v[0] = f2bf(a.x); v[1] = f2bf(a.y); v[2] = f2bf(a.z); v[3] = f2bf(a.w);
  v[4] = f2bf(b.x); v[5] = f2bf(b.y); v[6] = f2bf(b.z); v[7] = f2bf(b.w);
  return v;
}

// ---------------- merged conversion kernel ----------------
// ranges (in 8-elem groups): [0,320000) edge_ctx ; [320000,385536) W_pe ;
// [385536,909824) W_pc ; [909824,942592) W_cc (padded 51->64 rows)
__global__ void k_prep(const float* __restrict__ ec, const float* __restrict__ wpe,
                       const float* __restrict__ wpc, const float* __restrict__ wcc,
                       u16* __restrict__ ecb, u16* __restrict__ wpeb,
                       u16* __restrict__ wpcb, u16* __restrict__ wccb) {
  int i = blockIdx.x * 256 + threadIdx.x;
  if (i < 320000) {
    *(u16x8*)(ecb + (long)i * 8) = cvt8(ec + (long)i * 8);
  } else if (i < 385536) {
    int j = i - 320000;
    *(u16x8*)(wpeb + (long)j * 8) = cvt8(wpe + (long)j * 8);
  } else if (i < 909824) {
    int j = i - 385536;
    *(u16x8*)(wpcb + (long)j * 8) = cvt8(wpc + (long)j * 8);
  } else if (i < 942592) {
    int j = i - 909824;
    long base = (long)j * 8;
    int row = (int)(base >> 12);
    int col = (int)(base & 4095);
    u16x8 v;
    if (row < 51) {
      v = cvt8(wcc + (long)row * 4096 + col);
    } else {
#pragma unroll
      for (int k = 0; k < 8; ++k) v[k] = 0;
    }
    *(u16x8*)(wccb + base) = v;
  }
}

// one 128x128x32 compute step: 8 ds_read_b128 + 16 MFMA (setprio'd)
__device__ __forceinline__ void cstep(const char* sA, const char* sB,
                                      const int (&aOff)[4], const int (&bOff)[4],
                                      f32x4 (&acc)[4][4]) {
  bf16x8 af[4], bv[4];
#pragma unroll
  for (int mi = 0; mi < 4; ++mi) af[mi] = *(const bf16x8*)(sA + aOff[mi]);
#pragma unroll
  for (int ni = 0; ni < 4; ++ni) bv[ni] = *(const bf16x8*)(sB + bOff[ni]);
  __builtin_amdgcn_s_setprio(1);
#pragma unroll
  for (int mi = 0; mi < 4; ++mi)
#pragma unroll
    for (int ni = 0; ni < 4; ++ni)
      acc[mi][ni] = mfma16(af[mi], bv[ni], acc[mi][ni]);
  __builtin_amdgcn_s_setprio(0);
}

// one 128x128x64 compute step: 16 ds_read_b128 + 32 MFMA
__device__ __forceinline__ void cstep64(const char* buf,
                                        const int (&aOff)[4][2], const int (&bOff)[4][2],
                                        f32x4 (&acc)[4][4]) {
  bf16x8 af[4][2], bv[4][2];
#pragma unroll
  for (int mi = 0; mi < 4; ++mi)
#pragma unroll
    for (int ks = 0; ks < 2; ++ks) af[mi][ks] = *(const bf16x8*)(buf + aOff[mi][ks]);
#pragma unroll
  for (int ni = 0; ni < 4; ++ni)
#pragma unroll
    for (int ks = 0; ks < 2; ++ks) bv[ni][ks] = *(const bf16x8*)(buf + bOff[ni][ks]);
  __builtin_amdgcn_s_setprio(1);
#pragma unroll
  for (int ks = 0; ks < 2; ++ks)
#pragma unroll
    for (int mi = 0; mi < 4; ++mi)
#pragma unroll
      for (int ni = 0; ni < 4; ++ni)
        acc[mi][ni] = mfma16(af[mi][ks], bv[ni][ks], acc[mi][ni]);
  __builtin_amdgcn_s_setprio(0);
}

// ---------------- GEMM1: edge_rep = relu(edge_ctx @ W_pe.T + b_pe) -> bf16 ----------------
__global__ __launch_bounds__(256, 2) void k_gemm1(const u16* __restrict__ A, const u16* __restrict__ B,
                                                  const float* __restrict__ bias, u16* __restrict__ outp) {
  __shared__ char lds[65536];  // 4 bufs x (A 8K + B 8K)
  int bx = blockIdx.x;
  int rb = bx >> 3, nb = bx & 7;
  int rowBase = rb * 128, nBase = nb * 128;
  int t = threadIdx.x, lane = t & 63, wid = t >> 6;
  int wr = wid >> 1, wc = wid & 1, lm = lane & 15, lg = lane >> 4;
  int ar0 = t >> 2, ar1 = 64 + ar0, c4 = t & 3;
  int sw0 = (c4 * 16) ^ (((ar0 >> 1) & 3) << 4);
  int sw1 = (c4 * 16) ^ (((ar1 >> 1) & 3) << 4);
  const char* aS0 = (const char*)(A + (long)min(rowBase + ar0, 4999) * 512) + sw0;
  const char* aS1 = (const char*)(A + (long)min(rowBase + ar1, 4999) * 512) + sw1;
  const char* bS0 = (const char*)(B + (long)(nBase + ar0) * 512) + sw0;
  const char* bS1 = (const char*)(B + (long)(nBase + ar1) * 512) + sw1;
  int t16 = t * 16;
  int aOff[4], bOff[4];
#pragma unroll
  for (int mi = 0; mi < 4; ++mi) { int r = wr * 64 + mi * 16 + lm; aOff[mi] = r * 64 + ((lg * 16) ^ (((r >> 1) & 3) << 4)); }
#pragma unroll
  for (int ni = 0; ni < 4; ++ni) { int r = wc * 64 + ni * 16 + lm; bOff[ni] = r * 64 + ((lg * 16) ^ (((r >> 1) & 3) << 4)); }
  f32x4 acc[4][4] = {};

#define STAGE_G(k, sb) do { \
    gl16(aS0 + (k) * 2, (sb) + t16); gl16(aS1 + (k) * 2, (sb) + 4096 + t16); \
    gl16(bS0 + (k) * 2, (sb) + 8192 + t16); gl16(bS1 + (k) * 2, (sb) + 12288 + t16); \
  } while (0)

  STAGE_G(0, lds);
  STAGE_G(32, lds + 16384);
  STAGE_G(64, lds + 32768);

  int cur = 0, stg = 3;
  for (int kt = 0; kt < 16; ++kt) {
    if (kt < 13) {
      char* sb = lds + stg * 16384;
      STAGE_G((kt + 3) * 32, sb);
    }
    if (kt < 13)       asm volatile("s_waitcnt vmcnt(12)" ::: "memory");
    else if (kt == 13) asm volatile("s_waitcnt vmcnt(8)" ::: "memory");
    else if (kt == 14) asm volatile("s_waitcnt vmcnt(4)" ::: "memory");
    else               asm volatile("s_waitcnt vmcnt(0)" ::: "memory");
    __builtin_amdgcn_s_barrier();
    char* cb = lds + cur * 16384;
    cstep(cb, cb + 8192, aOff, bOff, acc);
    __builtin_amdgcn_s_barrier();
    cur = (cur == 3) ? 0 : cur + 1;
    stg = (stg == 3) ? 0 : stg + 1;
  }
#undef STAGE_G

#pragma unroll
  for (int mi = 0; mi < 4; ++mi)
#pragma unroll
    for (int ni = 0; ni < 4; ++ni) {
      int n = nBase + wc * 64 + ni * 16 + lm;
      float bvv = bias[n];
#pragma unroll
      for (int rg = 0; rg < 4; ++rg) {
        int r = rowBase + wr * 64 + mi * 16 + lg * 4 + rg;
        if (r < 5000) {
          float v = acc[mi][ni][rg] + bvv;
          v = v > 0.f ? v : 0.f;
          outp[(long)r * 1024 + n] = f2bf(v);
        }
      }
    }
}

// ---------------- GEMM2': H = head_rep @ W_pc[:,:512].T + b_pc ; T = tail_rep @ W_pc[:,512:].T ----------------
// BK=64, depth-2 double buffer, counted vmcnt(8). grid = 2560 (h x 40 rb x 32 nb).
__global__ __launch_bounds__(256, 2) void k_gemm2(const u16* __restrict__ erep, const u16* __restrict__ wpc,
                                                  const float* __restrict__ bpc, u16* __restrict__ Hout,
                                                  u16* __restrict__ Tout) {
  __shared__ char lds[65536];  // 2 bufs x (A 16K + B 16K)
  int bx = blockIdx.x;
  int h = (bx >= 1280) ? 1 : 0;
  int rr = bx - h * 1280;
  int rb = rr >> 5, nb = rr & 31;
  int rowBase = rb * 128, nBase = nb * 128;
  u16* outp = h ? Tout : Hout;
  int t = threadIdx.x, lane = t & 63, wid = t >> 6;
  int wr = wid >> 1, wc = wid & 1, lm = lane & 15, lg = lane >> 4;
  int ar = t >> 3, c8 = t & 7;        // staging: row ar (+32*i), 16B-chunk c8 of a 128B row
  int srcswz = ((c8 ^ (ar & 7)) << 4);
  const char* aP[4];
  const char* bP[4];
#pragma unroll
  for (int i = 0; i < 4; ++i) {
    int Ra = min(rowBase + i * 32 + ar, 4999);
    aP[i] = (const char*)(erep + (long)Ra * 1024 + h * 512) + srcswz;
    int Rb = nBase + i * 32 + ar;
    bP[i] = (const char*)(wpc + (long)Rb * 1024 + h * 512) + srcswz;
  }
  int t16 = t * 16;
  int aOff[4][2], bOff[4][2];
#pragma unroll
  for (int mi = 0; mi < 4; ++mi)
#pragma unroll
    for (int ks = 0; ks < 2; ++ks) {
      int r = wr * 64 + mi * 16 + lm;
      aOff[mi][ks] = r * 128 + (((ks * 4 + lg) ^ (r & 7)) << 4);
    }
#pragma unroll
  for (int ni = 0; ni < 4; ++ni)
#pragma unroll
    for (int ks = 0; ks < 2; ++ks) {
      int r = wc * 64 + ni * 16 + lm;
      bOff[ni][ks] = 16384 + r * 128 + (((ks * 4 + lg) ^ (r & 7)) << 4);
    }
  f32x4 acc[4][4] = {};

#define STAGE2(kk, buf) do { \
    _Pragma("unroll") \
    for (int i = 0; i < 4; ++i) { \
      gl16(aP[i] + (kk) * 2, (buf) + i * 4096 + t16); \
      gl16(bP[i] + (kk) * 2, (buf) + 16384 + i * 4096 + t16); \
    } \
  } while (0)

  STAGE2(0, lds);
  for (int kt = 0; kt < 8; ++kt) {
    if (kt < 7) STAGE2((kt + 1) * 64, lds + (((kt + 1) & 1) ? 32768 : 0));
    if (kt < 7) asm volatile("s_waitcnt vmcnt(8)" ::: "memory");
    else        asm volatile("s_waitcnt vmcnt(0)" ::: "memory");
    __builtin_amdgcn_s_barrier();
    cstep64(lds + ((kt & 1) ? 32768 : 0), aOff, bOff, acc);
    __builtin_amdgcn_s_barrier();
  }
#undef STAGE2

#pragma unroll
  for (int mi = 0; mi < 4; ++mi)
#pragma unroll
    for (int ni = 0; ni < 4; ++ni) {
      int n = nBase + wc * 64 + ni * 16 + lm;
      float bvv = h ? 0.f : bpc[n];
#pragma unroll
      for (int rg = 0; rg < 4; ++rg) {
        int r = rowBase + wr * 64 + mi * 16 + lg * 4 + rg;
        if (r < 5000) {
          float v = acc[mi][ni][rg] + bvv;
          outp[(long)r * 4096 + n] = f2bf(v);
        }
      }
    }
}

// ---------------- final: P = (H[hi] + T[ti]) * union ; partial[ps] = P_slice @ W_cc.T ----------------
// grid = 313 row-blocks (64 rows) x 8 pc-slices (512 cols, 4 chunks of 128). 256 threads, 4 waves.
// Chunk-pipelined: double-buffered sU, ONE lgkm-barrier per chunk, next chunk's loads
// (H, T, AND union) issued before the barrier so they ride under GEMM3. (R14 best-measured)
__global__ __launch_bounds__(256) void k_final(
    const u16* __restrict__ H, const u16* __restrict__ T,
    const u16* __restrict__ wcc,   // [64][4096] bf16 padded
    const float* __restrict__ un,  // [20000][4096] f32
    const int* __restrict__ pidx,
    float* __restrict__ partial) { // [8][20000][64] f32
  __shared__ char sU[2][16384];   // [64][128] bf16 swizzled, double-buffered
  int bx = blockIdx.x;
  int rb = bx >> 3, ps = bx & 7;
  int rowBase = rb * 64;
  int t = threadIdx.x, lane = t & 63, wid = t >> 6;
  int lm = lane & 15, lg = lane >> 4;
  int r16 = t >> 4, c16 = t & 15;

  // u32 byte offsets for the 4 gathered rows this thread touches (16 lanes/row -> 256B coalesced)
  u32 hoff[4], toff[4], uoff[4];
#pragma unroll
  for (int p = 0; p < 4; ++p) {
    int rG = min(rowBase + p * 16 + r16, 19999);
    hoff[p] = (u32)pidx[2 * rG] * 8192u + (u32)c16 * 16u;
    toff[p] = (u32)pidx[2 * rG + 1] * 8192u + (u32)c16 * 16u;
    uoff[p] = (u32)rG * 16384u + (u32)c16 * 32u;
  }
  const char* Hc = (const char*)H;
  const char* Tc = (const char*)T;
  const char* Uc = (const char*)un;
  int pc0 = ps * 512;

  u16x8 h8[4], t8[4];
  float4 u0[4], u1[4];

#define ISSUE(pcB) do { \
    _Pragma("unroll") \
    for (int p = 0; p < 4; ++p) { \
      h8[p] = *(const u16x8*)(Hc + hoff[p] + (u32)(pcB) * 2u); \
      t8[p] = *(const u16x8*)(Tc + toff[p] + (u32)(pcB) * 2u); \
      u0[p] = *(const float4*)(Uc + uoff[p] + (u32)(pcB) * 4u); \
      u1[p] = *(const float4*)(Uc + uoff[p] + (u32)(pcB) * 4u + 16u); \
    } \
  } while (0)

  f32x4 outAcc[4] = {};

  ISSUE(pc0);  // chunk 0 loads

  for (int chk = 0; chk < 4; ++chk) {
    int pcBase = pc0 + chk * 128;
    asm volatile("s_waitcnt vmcnt(0)" ::: "memory");  // chunk's loads arrived
    char* sUb = sU[chk & 1];
#pragma unroll
    for (int p = 0; p < 4; ++p) {
      int r = p * 16 + r16;
      float uu[8];
      *(float4*)(uu) = u0[p];
      *(float4*)(uu + 4) = u1[p];
      u16x8 pv;
#pragma unroll
      for (int j = 0; j < 8; ++j)
        pv[j] = f2bf((bf2f(h8[p][j]) + bf2f(t8[p][j])) * uu[j]);
      *(u16x8*)(sUb + r * 256 + ((c16 * 16) ^ ((r & 7) << 4))) = pv;
    }
    if (chk < 3) ISSUE(pcBase + 128);  // prefetch next chunk; rides under barrier+GEMM3
    asm volatile("s_waitcnt lgkmcnt(0)" ::: "memory");
    __builtin_amdgcn_s_barrier();      // sU[chk&1] writes visible; prev buffer freed

    // GEMM3 partial: outAcc += sU(64x128) @ W_cc_chunk(64x128)^T (wave owns rows wid*16..+16)
#pragma unroll
    for (int kb = 0; kb < 4; ++kb) {
      int r = wid * 16 + lm;
      bf16x8 aU = *(const bf16x8*)(sUb + r * 256 + ((kb * 64 + lg * 16) ^ ((r & 7) << 4)));
      bf16x8 bW[4];
#pragma unroll
      for (int ni = 0; ni < 4; ++ni)
        bW[ni] = *(const bf16x8*)(wcc + (long)(ni * 16 + lm) * 4096 + pcBase + kb * 32 + lg * 8);
      __builtin_amdgcn_s_setprio(1);
#pragma unroll
      for (int ni = 0; ni < 4; ++ni)
        outAcc[ni] = mfma16(aU, bW[ni], outAcc[ni]);
      __builtin_amdgcn_s_setprio(0);
    }
  }
#undef ISSUE

  // write-once partial slice (no atomics)
#pragma unroll
  for (int rg = 0; rg < 4; ++rg) {
    int r = wid * 16 + lg * 4 + rg;
    int rG = rowBase + r;
    if (rG < 20000) {
      long base = ((long)ps * 20000 + rG) * 64;
#pragma unroll
      for (int ni = 0; ni < 4; ++ni) {
        int c = ni * 16 + lm;
        if (c < 51) partial[base + c] = outAcc[ni][rg];
      }
    }
  }
}

// ---------------- reduce: out = sum_ps partial + b_cc + freq ----------------
__global__ void k_red(const float* __restrict__ partial, const float* __restrict__ bcc,
                      const float* __restrict__ freq, const int* __restrict__ preds,
                      const int* __restrict__ pidx, float* __restrict__ outp) {
  int idx = blockIdx.x * 256 + threadIdx.x;   // over 20000*64
  if (idx >= 20000 * 64) return;
  int row = idx >> 6, c = idx & 63;
  if (c >= 51) return;
  float s = 0.f;
#pragma unroll
  for (int i = 0; i < 8; ++i) s += partial[((long)i * 20000 + row) * 64 + c];
  int lbl = preds[pidx[2 * row]] * 151 + preds[pidx[2 * row + 1]];
  outp[(long)row * 51 + c] = s + bcc[c] + freq[(long)lbl * 51 + c];
}

extern "C" void kernel_launch(void* const* d_in, const int* in_sizes, int n_in,
                              void* d_out, int out_size, void* d_ws, size_t ws_size,
                              hipStream_t stream) {
  const float* edge_ctx = (const float*)d_in[0];
  const float* unionf   = (const float*)d_in[1];
  const float* W_pe     = (const float*)d_in[2];
  const float* b_pe     = (const float*)d_in[3];
  const float* W_pc     = (const float*)d_in[4];
  const float* b_pc     = (const float*)d_in[5];
  const float* W_cc     = (const float*)d_in[6];
  const float* b_cc     = (const float*)d_in[7];
  const float* freq     = (const float*)d_in[8];
  const int*   preds    = (const int*)d_in[9];
  const int*   pidx     = (const int*)d_in[10];
  float* out = (float*)d_out;
  char* ws = (char*)d_ws;

  u16* Hb    = (u16*)(ws + 0);           // 5000*4096 bf16 = 40,960,000 B
  u16* Tb    = (u16*)(ws + 40960000);    // 5000*4096 bf16
  u16* erep  = (u16*)(ws + 81920000);    // 5000*1024 bf16
  u16* wpcb  = (u16*)(ws + 92160000);    // 4096*1024 bf16
  u16* wccb  = (u16*)(ws + 100548608);   // 64*4096  bf16
  u16* ecb   = (u16*)(ws + 101072896);   // 5000*512 bf16
  u16* wpeb  = (u16*)(ws + 106192896);   // 1024*512 bf16
  float* par = (float*)(ws + 107241472); // 8*20000*64 f32 = 40,960,000 B (total ~148.2 MB)

  k_prep<<<3682, 256, 0, stream>>>(edge_ctx, W_pe, W_pc, W_cc, ecb, wpeb, wpcb, wccb);
  k_gemm1<<<320, 256, 0, stream>>>(ecb, wpeb, b_pe, erep);
  k_gemm2<<<2560, 256, 0, stream>>>(erep, wpcb, b_pc, Hb, Tb);
  k_final<<<2504, 256, 0, stream>>>(Hb, Tb, wccb, unionf, pidx, par);
  k_red<<<5000, 256, 0, stream>>>(par, b_cc, freq, preds, pidx, out);
}